// Round 7
// baseline (235.217 us; speedup 1.0000x reference)
//
#include <hip/hip_runtime.h>
#include <hip/hip_cooperative_groups.h>
#include <stdint.h>

namespace cg = cooperative_groups;

#define N 4096
#define B 2
#define D 128
#define LOG2E 1.4426950408889634f

typedef float f32x4 __attribute__((ext_vector_type(4)));

__device__ __forceinline__ float lrelu(float t) { return t > 0.f ? t : 0.01f * t; }

// Single fused cooperative kernel. 512 blocks x 256 threads.
// Residency: LDS ~34.6KB (<=160/2 per CU), VGPR<=256 via launch_bounds(256,2)
// -> 2 blocks/CU guaranteed co-resident (LDS-bound max is 4/CU), grid 512 OK.
// Block bk owns 16 rows row0=bk*16 (256 blocks per batch). Wave w owns local
// rows w*4..w*4+3 for the row-dot and denominator phases.
__global__ __launch_bounds__(256, 2) void kfused(
    const float* __restrict__ x,      // [B*N, D]
    const float* __restrict__ Wd,     // [D]
    const float* __restrict__ bd,     // [1]
    const float* __restrict__ Wa,     // [D, D]
    const float* __restrict__ w_l,    // [D]
    const float* __restrict__ w_r,    // [D]
    float* __restrict__ colR,         // ws [B*N]  r in exp2 domain
    float* __restrict__ out_dem,      // [B*N] (start of d_out)
    float* __restrict__ out_g) {      // [B,N,N]
    __shared__ float sFp[N];          // 16KB  exp2(r_j - rmax)
    __shared__ float sFm[N];          // 16KB  exp2(0.01*(r_j - rmax))
    __shared__ float uLR[2][D];       // u_l, u_r
    __shared__ float sWd[D];
    __shared__ float redm[4];
    __shared__ float4 rowfacS[16];    // (thr, Ep*sc, Em*sc, -) per local row

    int t = threadIdx.x;
    int lane = t & 63;
    int w = t >> 6;
    int bk = blockIdx.x;
    int row0 = bk << 4;               // global row base (includes batch)
    int b = bk >> 8;                  // batch

    // ---- Phase A: u_l[d]=sum_e Wa[e,d]*w_l[e]; u_r likewise (redundant/block).
    {
        int d = t & 127;
        int sel = t >> 7;                      // wave-uniform: 0->l, 1->r
        const float* wv = sel ? w_r : w_l;
        float acc = 0.f;
        #pragma unroll 8
        for (int e = 0; e < 128; ++e)
            acc += Wa[e * 128 + d] * wv[e];    // coalesced 512B/wave per e
        uLR[sel][d] = acc;
        if (t < 128) sWd[t] = Wd[t];
    }
    __syncthreads();

    // ---- Phase B: own 16 rows -> dem (regs+out), l (regs), r -> colR (global).
    float lq[4], demq[4];
    {
        float2 ul2 = ((const float2*)uLR[0])[lane];
        float2 ur2 = ((const float2*)uLR[1])[lane];
        float2 wd2 = ((const float2*)sWd)[lane];
        #pragma unroll
        for (int rr = 0; rr < 4; ++rr) {
            int row = row0 + w * 4 + rr;
            float2 xv = ((const float2*)(x + (size_t)row * D))[lane];
            float pl = xv.x * ul2.x + xv.y * ul2.y;
            float pr = xv.x * ur2.x + xv.y * ur2.y;
            float pd = xv.x * wd2.x + xv.y * wd2.y;
            #pragma unroll
            for (int m = 32; m >= 1; m >>= 1) {
                pl += __shfl_xor(pl, m, 64);
                pr += __shfl_xor(pr, m, 64);
                pd += __shfl_xor(pd, m, 64);
            }
            demq[rr] = 1.f / (1.f + __expf(-(pd + bd[0])));
            lq[rr] = pl * LOG2E;               // exp2 domain
            if (lane == 0) {
                out_dem[row] = demq[rr];
                colR[row] = pr * LOG2E;
            }
        }
    }
    __threadfence();          // device-scope release of colR before grid sync
    cg::this_grid().sync();

    // ---- Phase C: batch rmax (block-redundant) + LDS factor tables.
    float rloc[16];
    {
        const float* rb = colR + ((size_t)b << 12);
        float m = -3.402823466e38f;
        #pragma unroll
        for (int k = 0; k < 16; ++k) {
            rloc[k] = rb[t + k * 256];         // coalesced, L2-hot (16KB/batch)
            m = fmaxf(m, rloc[k]);
        }
        #pragma unroll
        for (int s = 32; s >= 1; s >>= 1) m = fmaxf(m, __shfl_xor(m, s, 64));
        if (lane == 0) redm[w] = m;
    }
    __syncthreads();
    float rmax = fmaxf(fmaxf(redm[0], redm[1]), fmaxf(redm[2], redm[3]));
    #pragma unroll
    for (int k = 0; k < 16; ++k) {
        float dd = rloc[k] - rmax;
        sFp[t + k * 256] = exp2f(dd);
        sFm[t + k * 256] = exp2f(0.01f * dd);
    }
    __syncthreads();

    // ---- Phase D: denominators. pos test via threshold (exp2 monotone):
    // l + r_j > 0  <=>  Fp_j > exp2(-(l + rmax)).
    {
        float thr[4];
        #pragma unroll
        for (int rr = 0; rr < 4; ++rr) thr[rr] = exp2f(-(lq[rr] + rmax));
        float s1[4] = {0.f, 0.f, 0.f, 0.f}, s2[4] = {0.f, 0.f, 0.f, 0.f};
        #pragma unroll 4
        for (int k = 0; k < 16; ++k) {
            int idx = lane + k * 64;           // float4-col 0..1023
            float4 fp = ((const float4*)sFp)[idx];
            float4 fm = ((const float4*)sFm)[idx];
            #pragma unroll
            for (int rr = 0; rr < 4; ++rr) {
                bool p0 = fp.x > thr[rr]; s1[rr] += p0 ? fp.x : 0.f; s2[rr] += p0 ? 0.f : fm.x;
                bool p1 = fp.y > thr[rr]; s1[rr] += p1 ? fp.y : 0.f; s2[rr] += p1 ? 0.f : fm.y;
                bool p2 = fp.z > thr[rr]; s1[rr] += p2 ? fp.z : 0.f; s2[rr] += p2 ? 0.f : fm.z;
                bool p3 = fp.w > thr[rr]; s1[rr] += p3 ? fp.w : 0.f; s2[rr] += p3 ? 0.f : fm.w;
            }
        }
        #pragma unroll
        for (int s = 32; s >= 1; s >>= 1) {
            #pragma unroll
            for (int rr = 0; rr < 4; ++rr) {
                s1[rr] += __shfl_xor(s1[rr], s, 64);
                s2[rr] += __shfl_xor(s2[rr], s, 64);
            }
        }
        if (lane == 0) {
            #pragma unroll
            for (int rr = 0; rr < 4; ++rr) {
                float t0 = lq[rr] + rmax;
                float m0 = lrelu(t0);          // true row max (lrelu monotone)
                float Ep = exp2f(t0 - m0);
                float Em = exp2f(0.01f * t0 - m0);
                float sc = demq[rr] / (Ep * s1[rr] + Em * s2[rr]);
                rowfacS[w * 4 + rr] = make_float4(thr[rr], Ep * sc, Em * sc, 0.f);
            }
        }
    }
    __syncthreads();

    // ---- Phase E: write 16 rows x 4096 cols. Thread owns float4-col idx;
    // lanes consecutive -> 1KB/wave contiguous stores per (it,ri).
    float thv[16], ePv[16], eMv[16];
    #pragma unroll
    for (int ri = 0; ri < 16; ++ri) {
        float4 rf = rowfacS[ri];
        thv[ri] = rf.x; ePv[ri] = rf.y; eMv[ri] = rf.z;
    }
    f32x4* outp = (f32x4*)out_g + ((size_t)row0 << 10);
    #pragma unroll
    for (int it = 0; it < 4; ++it) {
        int idx = it * 256 + t;
        float4 fp = ((const float4*)sFp)[idx];
        float4 fm = ((const float4*)sFm)[idx];
        #pragma unroll
        for (int ri = 0; ri < 16; ++ri) {
            f32x4 o;
            o.x = fp.x > thv[ri] ? ePv[ri] * fp.x : eMv[ri] * fm.x;
            o.y = fp.y > thv[ri] ? ePv[ri] * fp.y : eMv[ri] * fm.y;
            o.z = fp.z > thv[ri] ? ePv[ri] * fp.z : eMv[ri] * fm.z;
            o.w = fp.w > thv[ri] ? ePv[ri] * fp.w : eMv[ri] * fm.w;
            outp[((size_t)ri << 10) + idx] = o;
        }
    }
}

extern "C" void kernel_launch(void* const* d_in, const int* in_sizes, int n_in,
                              void* d_out, int out_size, void* d_ws, size_t ws_size,
                              hipStream_t stream) {
    // inputs: 0 embed_feat(f32 B*N*D), 1 predict_G(int,ignored), 2 W_demand(f32 D),
    //         3 b_demand(f32 1), 4 Wa(f32 D*D), 5 w_l(f32 D), 6 w_r(f32 D)
    const float* x  = (const float*)d_in[0];
    const float* Wd = (const float*)d_in[2];
    const float* bd = (const float*)d_in[3];
    const float* Wa = (const float*)d_in[4];
    const float* wl = (const float*)d_in[5];
    const float* wr = (const float*)d_in[6];

    float* colR = (float*)d_ws;     // 8192 floats (fully overwritten before read)

    float* out     = (float*)d_out;
    float* out_dem = out;           // [B*N]
    float* out_g   = out + B * N;   // [B,N,N] (byte off 32768, 16B-aligned)

    void* args[] = {(void*)&x, (void*)&Wd, (void*)&bd, (void*)&Wa, (void*)&wl,
                    (void*)&wr, (void*)&colR, (void*)&out_dem, (void*)&out_g};
    hipLaunchCooperativeKernel((const void*)kfused, dim3(512), dim3(256),
                               args, 0, stream);
}

// Round 8
// 166.603 us; speedup vs baseline: 1.4118x; 1.4118x over previous
//
#include <hip/hip_runtime.h>
#include <stdint.h>

#define N 4096
#define B 2
#define D 128
#define LOG2E 1.4426950408889634f

typedef float f32x4 __attribute__((ext_vector_type(4)));

__device__ __forceinline__ float lrelu(float t) { return t > 0.f ? t : 0.01f * t; }

// K1: u_l[d] = sum_e Wa[e*D+d]*w_l[e]; u_r likewise. 1 block x 256 threads.
__global__ __launch_bounds__(256) void k1_uvec(
    const float* __restrict__ Wa,
    const float* __restrict__ w_l,
    const float* __restrict__ w_r,
    float* __restrict__ u) {          // u[0..D)=u_l, u[D..2D)=u_r
    __shared__ float2 pl[4][64];
    __shared__ float2 pr[4][64];
    int t = threadIdx.x;
    int d2 = t & 63;
    int h = t >> 6;
    const float2* Wa2 = (const float2*)Wa;
    float2 al = make_float2(0.f, 0.f), ar = make_float2(0.f, 0.f);
    #pragma unroll 8
    for (int k = 0; k < 32; ++k) {
        int e = h * 32 + k;
        float2 w = Wa2[e * 64 + d2];       // Wa[e, 2*d2], Wa[e, 2*d2+1]
        float wl = w_l[e];
        float wr = w_r[e];
        al.x += w.x * wl; al.y += w.y * wl;
        ar.x += w.x * wr; ar.y += w.y * wr;
    }
    pl[h][d2] = al; pr[h][d2] = ar;
    __syncthreads();
    if (t < 64) {
        float2 s = make_float2(0.f, 0.f);
        #pragma unroll
        for (int hh = 0; hh < 4; ++hh) { s.x += pl[hh][t].x; s.y += pl[hh][t].y; }
        ((float2*)u)[t] = s;
    } else if (t < 128) {
        int dd = t - 64;
        float2 s = make_float2(0.f, 0.f);
        #pragma unroll
        for (int hh = 0; hh < 4; ++hh) { s.x += pr[hh][dd].x; s.y += pr[hh][dd].y; }
        ((float2*)(u + D))[dd] = s;
    }
}

// K2: one wave per row. demands -> d_out, l -> lv, r -> colR. No atomics.
__global__ __launch_bounds__(256) void k2_rows(
    const float* __restrict__ x,     // [B*N, D]
    const float* __restrict__ Wd,    // [D]
    const float* __restrict__ bd,    // [1]
    const float* __restrict__ u,     // [2*D]
    float* __restrict__ out_dem,     // [B*N] (start of d_out)
    float* __restrict__ lv,          // [B*N]  l in exp2 domain
    float* __restrict__ colR) {      // [B*N]  r in exp2 domain
    int lane = threadIdx.x & 63;
    int row = blockIdx.x * 4 + (threadIdx.x >> 6);
    float2 xv = ((const float2*)(x + (size_t)row * D))[lane];
    float2 ul2 = ((const float2*)u)[lane];
    float2 ur2 = ((const float2*)(u + D))[lane];
    float2 wv = ((const float2*)Wd)[lane];
    float pl = xv.x * ul2.x + xv.y * ul2.y;
    float pr = xv.x * ur2.x + xv.y * ur2.y;
    float pd = xv.x * wv.x + xv.y * wv.y;
    #pragma unroll
    for (int m = 32; m >= 1; m >>= 1) {
        pl += __shfl_xor(pl, m, 64);
        pr += __shfl_xor(pr, m, 64);
        pd += __shfl_xor(pd, m, 64);
    }
    if (lane == 0) {
        float dem = 1.f / (1.f + __expf(-(pd + bd[0])));
        out_dem[row] = dem;
        lv[row] = pl * LOG2E;            // exp2 domain (lrelu commutes with pos. scale)
        colR[row] = pr * LOG2E;
    }
}

// K2b: one block per batch. Block-reduce rmax over 4096 r values (zero atomics),
// then write SoA column factors: colFp[j]=exp2(r-rmax), colFm[j]=exp2(0.01*(r-rmax)).
__global__ __launch_bounds__(1024) void k2b_fpm(
    const float* __restrict__ colR,
    float* __restrict__ colFp,
    float* __restrict__ colFm,
    float* __restrict__ gmax) {        // [B] rmax
    __shared__ float red[16];
    int b = blockIdx.x;
    int tid = threadIdx.x;
    const float* rb = colR + (size_t)b * N;
    float r[4];
    float m = -3.402823466e38f;
    #pragma unroll
    for (int k = 0; k < 4; ++k) {
        r[k] = rb[tid + k * 1024];
        m = fmaxf(m, r[k]);
    }
    #pragma unroll
    for (int s = 32; s >= 1; s >>= 1) m = fmaxf(m, __shfl_xor(m, s, 64));
    if ((tid & 63) == 0) red[tid >> 6] = m;
    __syncthreads();
    float rmax = red[0];
    #pragma unroll
    for (int w = 1; w < 16; ++w) rmax = fmaxf(rmax, red[w]);
    if (tid == 0) gmax[b] = rmax;
    #pragma unroll
    for (int k = 0; k < 4; ++k) {
        float t = r[k] - rmax;
        colFp[(size_t)b * N + tid + k * 1024] = exp2f(t);
        colFm[(size_t)b * N + tid + k * 1024] = exp2f(0.01f * t);
    }
}

// K2c: denominator pass. 4 rows/block. S1 = sum_{l+r>0} Fp_j, S2 = sum_else Fm_j.
// Writes rowfac[row] = (thr, Ep*sc, Em*sc, 0) with sc = dem/(Ep*S1+Em*S2),
// thr = exp2(-(l+rmax)) so the writer's test is Fp_j > thr  <=>  l+r_j > 0.
__global__ __launch_bounds__(256) void k2c_den(
    const float* __restrict__ lv,
    const float* __restrict__ colR,
    const float* __restrict__ colFp,
    const float* __restrict__ colFm,
    const float* __restrict__ gmax,
    const float* __restrict__ dem_f,
    float4* __restrict__ rowfac) {        // [B*N]
    __shared__ float red[4][8];
    int tid = threadIdx.x;
    int b = blockIdx.x >> 10;
    int i0 = (blockIdx.x & 1023) << 2;
    const float4* r4 = (const float4*)(colR + (size_t)b * N);
    const float4* p4 = (const float4*)(colFp + (size_t)b * N);
    const float4* m4 = (const float4*)(colFm + (size_t)b * N);
    float rmax = gmax[b];
    int rowbase = b * N + i0;

    float l_[4];
    #pragma unroll
    for (int q = 0; q < 4; ++q) l_[q] = lv[rowbase + q];

    float s1[4] = {0.f, 0.f, 0.f, 0.f}, s2[4] = {0.f, 0.f, 0.f, 0.f};
    #pragma unroll 4
    for (int k = 0; k < N / 4 / 256; ++k) {
        float4 rv = r4[tid + k * 256];
        float4 fp = p4[tid + k * 256];
        float4 fm = m4[tid + k * 256];
        #pragma unroll
        for (int q = 0; q < 4; ++q) {
            float l = l_[q];
            s1[q] += (l + rv.x > 0.f) ? fp.x : 0.f;
            s2[q] += (l + rv.x > 0.f) ? 0.f : fm.x;
            s1[q] += (l + rv.y > 0.f) ? fp.y : 0.f;
            s2[q] += (l + rv.y > 0.f) ? 0.f : fm.y;
            s1[q] += (l + rv.z > 0.f) ? fp.z : 0.f;
            s2[q] += (l + rv.z > 0.f) ? 0.f : fm.z;
            s1[q] += (l + rv.w > 0.f) ? fp.w : 0.f;
            s2[q] += (l + rv.w > 0.f) ? 0.f : fm.w;
        }
    }
    #pragma unroll
    for (int m = 32; m >= 1; m >>= 1) {
        #pragma unroll
        for (int q = 0; q < 4; ++q) {
            s1[q] += __shfl_xor(s1[q], m, 64);
            s2[q] += __shfl_xor(s2[q], m, 64);
        }
    }
    int w = tid >> 6;
    if ((tid & 63) == 0) {
        #pragma unroll
        for (int q = 0; q < 4; ++q) { red[w][q] = s1[q]; red[w][4 + q] = s2[q]; }
    }
    __syncthreads();
    if (tid < 4) {
        int q = tid;
        float S1 = red[0][q] + red[1][q] + red[2][q] + red[3][q];
        float S2 = red[0][4 + q] + red[1][4 + q] + red[2][4 + q] + red[3][4 + q];
        float t0 = l_[q] + rmax;
        float m0 = lrelu(t0);             // true row max of lrelu(l+r) (monotone)
        float Ep = exp2f(t0 - m0);
        float Em = exp2f(0.01f * t0 - m0);
        float sc = dem_f[rowbase + q] / (Ep * S1 + Em * S2);
        float thr = exp2f(-t0);           // Fp_j > thr  <=>  l + r_j > 0
        rowfac[rowbase + q] = make_float4(thr, Ep * sc, Em * sc, 0.f);
    }
}

// K3s: shuffle-fed streaming writer — ZERO VMEM loads in the store loop.
// 1024 blocks x 256 threads = 4096 waves. Wave W = blk*4+w owns:
//   jc = W & 15  -> lane's fixed float4-column j4 = jc*64+lane
//   rg = W >> 4  -> 32 consecutive global rows
// Prologue: 3 col-factor loads (12 regs) + ONE float2/lane covering all 32
// rowfacs of the wave (lane 2k holds {thr_k, eP_k}, lane 2k+1 holds {eM_k,-}).
// Loop: row factors via __shfl (LDS pipe / lgkmcnt -> does NOT drain vmcnt);
// store data rotates through 8 independent f32x4 buffers (static idx after
// unroll) -> ~8 outstanding stores/wave, never drained by loads.
__global__ __launch_bounds__(256) void k3s_write(
    const float4* __restrict__ rowfac,   // [B*N] (thr, EpSc, EmSc, -)
    const float* __restrict__ colR,
    const float* __restrict__ colFp,
    const float* __restrict__ colFm,
    float* __restrict__ out_g) {         // [B,N,N] fp32 (16B-aligned)
    int W = blockIdx.x * 4 + (threadIdx.x >> 6);
    int lane = threadIdx.x & 63;
    int jc = W & 15;
    int rg = W >> 4;                     // 0..255
    int row0 = rg * 32;                  // global row b*N+i; stays in one batch
    int b = row0 >> 12;
    int j4 = jc * 64 + lane;             // float4-column 0..1023
    int cb = (b << 12) + (j4 << 2);
    float4 rv = *(const float4*)(colR + cb);
    float4 fp = *(const float4*)(colFp + cb);
    float4 fm = *(const float4*)(colFm + cb);
    // all 32 rowfacs of this wave, packed 2 lanes per row
    float2 rfl = ((const float2*)rowfac)[row0 * 2 + lane];
    f32x4* outp = (f32x4*)out_g + (size_t)row0 * 1024 + j4;
    f32x4 ob[8];
    #pragma unroll
    for (int k = 0; k < 32; ++k) {
        float thr = __shfl(rfl.x, 2 * k, 64);      // wave-uniform row factors
        float eP  = __shfl(rfl.y, 2 * k, 64);
        float eM  = __shfl(rfl.x, 2 * k + 1, 64);
        f32x4 o;
        o.x = fp.x > thr ? eP * fp.x : eM * fm.x;
        o.y = fp.y > thr ? eP * fp.y : eM * fm.y;
        o.z = fp.z > thr ? eP * fp.z : eM * fm.z;
        o.w = fp.w > thr ? eP * fp.w : eM * fm.w;
        ob[k & 7] = o;                   // 8-deep rotation: ~8 stores in flight
        outp[(size_t)k * 1024] = ob[k & 7];
    }
}

extern "C" void kernel_launch(void* const* d_in, const int* in_sizes, int n_in,
                              void* d_out, int out_size, void* d_ws, size_t ws_size,
                              hipStream_t stream) {
    // inputs: 0 embed_feat(f32 B*N*D), 1 predict_G(int,ignored), 2 W_demand(f32 D),
    //         3 b_demand(f32 1), 4 Wa(f32 D*D), 5 w_l(f32 D), 6 w_r(f32 D)
    const float* x  = (const float*)d_in[0];
    const float* Wd = (const float*)d_in[2];
    const float* bd = (const float*)d_in[3];
    const float* Wa = (const float*)d_in[4];
    const float* wl = (const float*)d_in[5];
    const float* wr = (const float*)d_in[6];

    float* ws = (float*)d_ws;
    float* u      = ws;                       // 256 floats
    float* lv     = ws + 256;                 // 8192
    float* colR   = ws + 256 + 8192;          // 8192 (byte off 33792, 16B-aligned)
    float* colFp  = colR + 8192;              // 8192
    float* colFm  = colFp + 8192;             // 8192
    float4* rowfac = (float4*)(colFm + 8192); // 8192 float4 (16B-aligned)
    float* gmax   = (float*)(rowfac + 8192);  // 2 floats  (~263 KB total)

    float* out     = (float*)d_out;
    float* out_dem = out;           // [B*N]
    float* out_g   = out + B * N;   // [B,N,N] (byte off 32768, 16B-aligned)

    hipLaunchKernelGGL(k1_uvec, dim3(1), dim3(256), 0, stream, Wa, wl, wr, u);
    hipLaunchKernelGGL(k2_rows, dim3(B * N / 4), dim3(256), 0, stream,
                       x, Wd, bd, u, out_dem, lv, colR);
    hipLaunchKernelGGL(k2b_fpm, dim3(B), dim3(1024), 0, stream,
                       colR, colFp, colFm, gmax);
    hipLaunchKernelGGL(k2c_den, dim3(B * N / 4), dim3(256), 0, stream,
                       lv, colR, colFp, colFm, gmax, out_dem, rowfac);
    hipLaunchKernelGGL(k3s_write, dim3(1024), dim3(256), 0, stream,
                       rowfac, colR, colFp, colFm, out_g);
}

// Round 9
// 151.432 us; speedup vs baseline: 1.5533x; 1.1002x over previous
//
#include <hip/hip_runtime.h>
#include <stdint.h>

#define N 4096
#define B 2
#define D 128
#define LOG2E 1.4426950408889634f

typedef float f32x4 __attribute__((ext_vector_type(4)));

__device__ __forceinline__ float lrelu(float t) { return t > 0.f ? t : 0.01f * t; }

// Node 1: fused u-vector + row dots. 512 blocks x 256 threads; block owns 16 rows.
// Phase A (validated in r7 kfused): every block redundantly computes
// u_l[d]=sum_e Wa[e,d]*w_l[e], u_r likewise (Wa is 64KB, L2-hot; 512x64KB=32MB L2).
// Phase B: wave w computes rows blk*16+w*4..+3: demands->out, l->lv, r->colR.
__global__ __launch_bounds__(256) void kA_rows(
    const float* __restrict__ x,      // [B*N, D]
    const float* __restrict__ Wd,     // [D]
    const float* __restrict__ bd,     // [1]
    const float* __restrict__ Wa,     // [D, D]
    const float* __restrict__ w_l,    // [D]
    const float* __restrict__ w_r,    // [D]
    float* __restrict__ out_dem,      // [B*N] (start of d_out)
    float* __restrict__ lv,           // [B*N]  l in exp2 domain
    float* __restrict__ colR) {       // [B*N]  r in exp2 domain
    __shared__ float uLR[2][D];
    __shared__ float sWd[D];
    int t = threadIdx.x;
    int lane = t & 63;
    int w = t >> 6;
    int row0 = blockIdx.x << 4;

    // Phase A
    {
        int d = t & 127;
        int sel = t >> 7;                      // wave-uniform: 0->l, 1->r
        const float* wv = sel ? w_r : w_l;
        float acc = 0.f;
        #pragma unroll 8
        for (int e = 0; e < 128; ++e)
            acc += Wa[e * 128 + d] * wv[e];    // coalesced, L2-hot
        uLR[sel][d] = acc;
        if (t < 128) sWd[t] = Wd[t];
    }
    __syncthreads();

    // Phase B
    float2 ul2 = ((const float2*)uLR[0])[lane];
    float2 ur2 = ((const float2*)uLR[1])[lane];
    float2 wd2 = ((const float2*)sWd)[lane];
    #pragma unroll
    for (int rr = 0; rr < 4; ++rr) {
        int row = row0 + w * 4 + rr;
        float2 xv = ((const float2*)(x + (size_t)row * D))[lane];
        float pl = xv.x * ul2.x + xv.y * ul2.y;
        float pr = xv.x * ur2.x + xv.y * ur2.y;
        float pd = xv.x * wd2.x + xv.y * wd2.y;
        #pragma unroll
        for (int m = 32; m >= 1; m >>= 1) {
            pl += __shfl_xor(pl, m, 64);
            pr += __shfl_xor(pr, m, 64);
            pd += __shfl_xor(pd, m, 64);
        }
        if (lane == 0) {
            out_dem[row] = 1.f / (1.f + __expf(-(pd + bd[0])));
            lv[row] = pl * LOG2E;            // exp2 domain (lrelu commutes w/ pos scale)
            colR[row] = pr * LOG2E;
        }
    }
}

// Node 2: rmax + factor tables (LDS) + denominators + CONTIGUOUS writer.
// 1024 blocks x 256 threads; block owns 8 adjacent rows (128KB contiguous output);
// wave w owns rows i0+2w, i0+2w+1 (32KB contiguous per wave).
// Write loop operands come from LDS only (lgkmcnt; never drains store vmcnt);
// stores are fully unrolled (8 independent data regs -> ~8 outstanding/wave).
// Factorization: out = (Fp_j > thr_i) ? eP_i*Fp_j : eM_i*Fm_j, with
//   Fp=exp2(r-rmax), Fm=exp2(0.01(r-rmax)), thr=exp2(-(l+rmax)),
//   eP=exp2(l+rmax-m0)*sc, eM=exp2(0.01(l+rmax)-m0)*sc, m0=lrelu(l+rmax),
//   sc=dem/(Ep*S1+Em*S2), S1=sum_{pos}Fp, S2=sum_{neg}Fm.
__global__ __launch_bounds__(256) void kB_write(
    const float* __restrict__ lv,
    const float* __restrict__ colR,
    const float* __restrict__ dem_f,      // demands (start of d_out)
    float* __restrict__ out_g) {          // [B,N,N] fp32 (16B-aligned)
    __shared__ float sFp[N];              // 16KB
    __shared__ float sFm[N];              // 16KB
    __shared__ float redm[4];
    int t = threadIdx.x;
    int lane = t & 63;
    int w = t >> 6;
    int i0 = blockIdx.x << 3;             // global row base (incl. batch)
    int b = i0 >> 12;

    // rmax (block-redundant, over the full batch) + tables into LDS
    const float4* rB = (const float4*)(colR + ((size_t)b << 12));
    float4 loc[4];
    float m = -3.402823466e38f;
    #pragma unroll
    for (int k = 0; k < 4; ++k) {
        loc[k] = rB[t + k * 256];          // coalesced, L2-hot (16KB/batch)
        m = fmaxf(fmaxf(m, fmaxf(loc[k].x, loc[k].y)), fmaxf(loc[k].z, loc[k].w));
    }
    #pragma unroll
    for (int s = 32; s >= 1; s >>= 1) m = fmaxf(m, __shfl_xor(m, s, 64));
    if (lane == 0) redm[w] = m;
    __syncthreads();
    float rmax = fmaxf(fmaxf(redm[0], redm[1]), fmaxf(redm[2], redm[3]));
    #pragma unroll
    for (int k = 0; k < 4; ++k) {
        int idx = t + k * 256;             // float4 index
        float4 v = loc[k];
        ((float4*)sFp)[idx] = make_float4(exp2f(v.x - rmax), exp2f(v.y - rmax),
                                          exp2f(v.z - rmax), exp2f(v.w - rmax));
        ((float4*)sFm)[idx] = make_float4(exp2f(0.01f * (v.x - rmax)),
                                          exp2f(0.01f * (v.y - rmax)),
                                          exp2f(0.01f * (v.z - rmax)),
                                          exp2f(0.01f * (v.w - rmax)));
    }
    __syncthreads();

    // per-wave: denominators for rows rA=i0+2w, rB=i0+2w+1
    int rowA = i0 + 2 * w;
    float lA = lv[rowA], lB = lv[rowA + 1];
    float tA = lA + rmax, tB = lB + rmax;
    float thrA = exp2f(-tA), thrB = exp2f(-tB);
    float s1a = 0.f, s2a = 0.f, s1b = 0.f, s2b = 0.f;
    #pragma unroll 4
    for (int seg = 0; seg < 16; ++seg) {
        int idx = seg * 64 + lane;
        float4 fp = ((const float4*)sFp)[idx];
        float4 fm = ((const float4*)sFm)[idx];
        s1a += (fp.x > thrA ? fp.x : 0.f) + (fp.y > thrA ? fp.y : 0.f)
             + (fp.z > thrA ? fp.z : 0.f) + (fp.w > thrA ? fp.w : 0.f);
        s2a += (fp.x > thrA ? 0.f : fm.x) + (fp.y > thrA ? 0.f : fm.y)
             + (fp.z > thrA ? 0.f : fm.z) + (fp.w > thrA ? 0.f : fm.w);
        s1b += (fp.x > thrB ? fp.x : 0.f) + (fp.y > thrB ? fp.y : 0.f)
             + (fp.z > thrB ? fp.z : 0.f) + (fp.w > thrB ? fp.w : 0.f);
        s2b += (fp.x > thrB ? 0.f : fm.x) + (fp.y > thrB ? 0.f : fm.y)
             + (fp.z > thrB ? 0.f : fm.z) + (fp.w > thrB ? 0.f : fm.w);
    }
    #pragma unroll
    for (int s = 32; s >= 1; s >>= 1) {
        s1a += __shfl_xor(s1a, s, 64);
        s2a += __shfl_xor(s2a, s, 64);
        s1b += __shfl_xor(s1b, s, 64);
        s2b += __shfl_xor(s2b, s, 64);
    }
    float m0A = lrelu(tA), m0B = lrelu(tB);
    float EpA = exp2f(tA - m0A), EmA = exp2f(0.01f * tA - m0A);
    float EpB = exp2f(tB - m0B), EmB = exp2f(0.01f * tB - m0B);
    float scA = dem_f[rowA] / (EpA * s1a + EmA * s2a);
    float scB = dem_f[rowA + 1] / (EpB * s1b + EmB * s2b);
    float ePA = EpA * scA, eMA = EmA * scA;
    float ePB = EpB * scB, eMB = EmB * scB;

    // Write: wave covers 32KB contiguous (2 rows); block 128KB; grid = linear
    // sweep of the 134MB output, fill-like. Zero VMEM loads in the loop.
    f32x4* outA = (f32x4*)(out_g + (size_t)rowA * N);
    #pragma unroll
    for (int q = 0; q < 4; ++q) {
        int idx = q * 64 + lane;
        float4 fp = ((const float4*)sFp)[idx];
        float4 fm = ((const float4*)sFm)[idx];
        f32x4 o;
        o.x = fp.x > thrA ? ePA * fp.x : eMA * fm.x;
        o.y = fp.y > thrA ? ePA * fp.y : eMA * fm.y;
        o.z = fp.z > thrA ? ePA * fp.z : eMA * fm.z;
        o.w = fp.w > thrA ? ePA * fp.w : eMA * fm.w;
        outA[idx] = o;
        f32x4 o2;
        o2.x = fp.x > thrB ? ePB * fp.x : eMB * fm.x;
        o2.y = fp.y > thrB ? ePB * fp.y : eMB * fm.y;
        o2.z = fp.z > thrB ? ePB * fp.z : eMB * fm.z;
        o2.w = fp.w > thrB ? ePB * fp.w : eMB * fm.w;
        outA[1024 + idx] = o2;
    }
}

extern "C" void kernel_launch(void* const* d_in, const int* in_sizes, int n_in,
                              void* d_out, int out_size, void* d_ws, size_t ws_size,
                              hipStream_t stream) {
    // inputs: 0 embed_feat(f32 B*N*D), 1 predict_G(int,ignored), 2 W_demand(f32 D),
    //         3 b_demand(f32 1), 4 Wa(f32 D*D), 5 w_l(f32 D), 6 w_r(f32 D)
    const float* x  = (const float*)d_in[0];
    const float* Wd = (const float*)d_in[2];
    const float* bd = (const float*)d_in[3];
    const float* Wa = (const float*)d_in[4];
    const float* wl = (const float*)d_in[5];
    const float* wr = (const float*)d_in[6];

    float* ws = (float*)d_ws;
    float* lv   = ws;                 // 8192 floats
    float* colR = ws + 8192;          // 8192 floats

    float* out     = (float*)d_out;
    float* out_dem = out;             // [B*N]
    float* out_g   = out + B * N;     // [B,N,N] (byte off 32768, 16B-aligned)

    hipLaunchKernelGGL(kA_rows, dim3(B * N / 16), dim3(256), 0, stream,
                       x, Wd, bd, Wa, wl, wr, out_dem, lv, colR);
    hipLaunchKernelGGL(kB_write, dim3(B * N / 8), dim3(256), 0, stream,
                       lv, colR, out_dem, out_g);
}